// Round 1
// baseline (359.061 us; speedup 1.0000x reference)
//
#include <hip/hip_runtime.h>

#define NROWS 16384
#define NC    2048
#define NB    2048
#define NT    256
#define EPT   8   // elements per thread (NC / NT)

// One block per row. Counting-sort by value bins + exact within-bin rank,
// then prefix-sum of descending-sorted labels -> LRAP row score.
__global__ __launch_bounds__(NT) void lrap_rows(const float* __restrict__ preds,
                                                const float* __restrict__ labels,
                                                float* __restrict__ rowsc)
{
    __shared__ unsigned int binstart[NB + 1];
    __shared__ unsigned int cursor[NB];
    __shared__ __align__(16) float skey[NC];
    __shared__ __align__(16) float slab[NC];
    __shared__ unsigned int uw[8];
    __shared__ float fw[16];

    const int t    = threadIdx.x;
    const int lane = t & 63;
    const int wid  = t >> 6;
    const int row  = blockIdx.x;

    const float* prow = preds  + (size_t)row * NC;
    const float* lrow = labels + (size_t)row * NC;

    // ---- load 8 elements/thread, fully coalesced float4 ----
    float4 p0 = ((const float4*)prow)[t];
    float4 p1 = ((const float4*)prow)[t + NT];
    float4 l0 = ((const float4*)lrow)[t];
    float4 l1 = ((const float4*)lrow)[t + NT];

    float pv[EPT]  = {p0.x, p0.y, p0.z, p0.w, p1.x, p1.y, p1.z, p1.w};
    float lvf[EPT] = {l0.x, l0.y, l0.z, l0.w, l1.x, l1.y, l1.z, l1.w};

    // ---- histogram (cursor doubles as hist) ----
    #pragma unroll
    for (int j = 0; j < EPT; ++j) cursor[t * EPT + j] = 0u;
    __syncthreads();

    const float SCALE = (float)NB / 12.0f;   // bins over [-6, 6], descending order
    int bb[EPT];
    #pragma unroll
    for (int j = 0; j < EPT; ++j) {
        int b = (int)((6.0f - pv[j]) * SCALE);
        b = b < 0 ? 0 : (b > NB - 1 ? NB - 1 : b);
        bb[j] = b;
        atomicAdd(&cursor[b], 1u);
    }
    __syncthreads();

    // ---- exclusive scan hist -> binstart ----
    unsigned int run[EPT];
    unsigned int s = 0;
    #pragma unroll
    for (int j = 0; j < EPT; ++j) { run[j] = s; s += cursor[t * EPT + j]; }
    unsigned int x = s;
    #pragma unroll
    for (int d = 1; d < 64; d <<= 1) {
        unsigned int y = __shfl_up(x, (unsigned)d, 64);
        if (lane >= d) x += y;
    }
    if (lane == 63) uw[wid] = x;
    __syncthreads();
    if (t == 0) {
        unsigned int a = 0;
        for (int w = 0; w < 4; ++w) { unsigned int v = uw[w]; uw[4 + w] = a; a += v; }
    }
    __syncthreads();
    unsigned int base = uw[4 + wid] + (x - s);
    #pragma unroll
    for (int j = 0; j < EPT; ++j) binstart[t * EPT + j] = base + run[j];
    if (t == 0) binstart[NB] = NC;
    __syncthreads();
    #pragma unroll
    for (int j = 0; j < EPT; ++j) cursor[t * EPT + j] = binstart[t * EPT + j];
    __syncthreads();

    // ---- scatter into bins (arbitrary order within bin) ----
    unsigned int pos[EPT];
    #pragma unroll
    for (int j = 0; j < EPT; ++j) pos[j] = atomicAdd(&cursor[bb[j]], 1u);
    #pragma unroll
    for (int j = 0; j < EPT; ++j) skey[pos[j]] = pv[j];
    __syncthreads();

    // ---- exact within-bin rank (strict total order via scatter-pos tie-break),
    //      write label at its final descending-pred position ----
    #pragma unroll
    for (int j = 0; j < EPT; ++j) {
        unsigned int b  = (unsigned int)bb[j];
        unsigned int s0 = binstart[b], s1 = binstart[b + 1];
        unsigned int myp = pos[j];
        float key = pv[j];
        unsigned int r = 0;
        for (unsigned int q = s0; q < s1; ++q) {
            float kq = skey[q];
            r += ((kq > key) || (kq == key && q < myp)) ? 1u : 0u;
        }
        slab[s0 + r] = (lvf[j] != 0.0f) ? 1.0f : 0.0f;
    }
    __syncthreads();

    // ---- inclusive scan over sorted labels + score accumulation ----
    float4 sa = ((const float4*)slab)[2 * t];
    float4 sb = ((const float4*)slab)[2 * t + 1];
    float fl[EPT] = {sa.x, sa.y, sa.z, sa.w, sb.x, sb.y, sb.z, sb.w};
    float inc[EPT];
    float cs = 0.f;
    #pragma unroll
    for (int j = 0; j < EPT; ++j) { cs += fl[j]; inc[j] = cs; }
    float fx = cs;
    #pragma unroll
    for (int d = 1; d < 64; d <<= 1) {
        float fy = __shfl_up(fx, (unsigned)d, 64);
        if (lane >= d) fx += fy;
    }
    if (lane == 63) fw[wid] = fx;
    __syncthreads();
    if (t == 0) {
        float a = 0.f;
        for (int w = 0; w < 4; ++w) { float v = fw[w]; fw[4 + w] = a; a += v; }
        fw[8] = a;  // k = total positives in row
    }
    __syncthreads();
    float fbase = fw[4 + wid] + (fx - cs);
    float part = 0.f;
    #pragma unroll
    for (int j = 0; j < EPT; ++j) {
        if (fl[j] != 0.f) part += (fbase + inc[j]) / (float)(t * EPT + j + 1);
    }
    #pragma unroll
    for (int d = 32; d >= 1; d >>= 1) part += __shfl_down(part, (unsigned)d, 64);
    if (lane == 0) fw[9 + wid] = part;
    __syncthreads();
    if (t == 0) {
        float tot = fw[9] + fw[10] + fw[11] + fw[12];
        float k = fw[8];
        rowsc[row] = (k > 0.f) ? (tot / k) : 0.f;
    }
}

__global__ __launch_bounds__(1024) void mean_reduce(const float* __restrict__ v,
                                                    float* __restrict__ out)
{
    __shared__ float ws[16];
    int t = threadIdx.x;
    float s = 0.f;
    for (int i = t; i < NROWS; i += 1024) s += v[i];
    int lane = t & 63, wid = t >> 6;
    #pragma unroll
    for (int d = 32; d >= 1; d >>= 1) s += __shfl_down(s, (unsigned)d, 64);
    if (lane == 0) ws[wid] = s;
    __syncthreads();
    if (t == 0) {
        float a = 0.f;
        for (int w = 0; w < 16; ++w) a += ws[w];
        out[0] = a / (float)NROWS;
    }
}

extern "C" void kernel_launch(void* const* d_in, const int* in_sizes, int n_in,
                              void* d_out, int out_size, void* d_ws, size_t ws_size,
                              hipStream_t stream)
{
    const float* preds  = (const float*)d_in[0];
    const float* labels = (const float*)d_in[1];
    float* rowsc = (float*)d_ws;   // NROWS floats of scratch

    lrap_rows<<<NROWS, NT, 0, stream>>>(preds, labels, rowsc);
    mean_reduce<<<1, 1024, 0, stream>>>(rowsc, (float*)d_out);
}

// Round 2
// 313.501 us; speedup vs baseline: 1.1453x; 1.1453x over previous
//
#include <hip/hip_runtime.h>

#define NROWS 16384
#define NC    2048
#define NB    2048
#define NT    256
#define EPT   8   // elements per thread (NC / NT)

// One block per row.
// Phase 1: packed histogram (all<<16 | pos) over NB logistic-CDF-equalized bins.
// Phase 2: packed exclusive scan -> per-bin (r_base, j_base).
// Phase 3: scatter {ordered_key, label} into bin segments.
// Phase 4: for positives only, exact within-bin rank among all & among positives,
//          accumulate (j_base+j_off+1)/(r_base+r_off+1). Divide by k. Done.
__global__ __launch_bounds__(NT) void lrap_rows(const float* __restrict__ preds,
                                                const float* __restrict__ labels,
                                                float* __restrict__ rowsc)
{
    __shared__ unsigned int binstart[NB + 1];   // packed exclusive cum: (all<<16)|pos
    __shared__ unsigned int cursor[NB];         // hist, then scatter cursor
    __shared__ __align__(16) uint2 skv[NC];     // {ordered key, label}
    __shared__ unsigned int uw[8];
    __shared__ float fw[4];

    const int t    = threadIdx.x;
    const int lane = t & 63;
    const int wid  = t >> 6;
    const int row  = blockIdx.x;

    const float* prow = preds  + (size_t)row * NC;
    const float* lrow = labels + (size_t)row * NC;

    // ---- coalesced float4 loads, 8 elem/thread ----
    float4 p0 = ((const float4*)prow)[t];
    float4 p1 = ((const float4*)prow)[t + NT];
    float4 l0 = ((const float4*)lrow)[t];
    float4 l1 = ((const float4*)lrow)[t + NT];
    float pv[EPT] = {p0.x, p0.y, p0.z, p0.w, p1.x, p1.y, p1.z, p1.w};
    float lv[EPT] = {l0.x, l0.y, l0.z, l0.w, l1.x, l1.y, l1.z, l1.w};

    #pragma unroll
    for (int j = 0; j < EPT; ++j) cursor[t * EPT + j] = 0u;
    __syncthreads();

    // ---- bin via logistic CDF (monotone decreasing in p), packed histogram ----
    int bb[EPT];
    unsigned int kk[EPT], lb[EPT];
    #pragma unroll
    for (int j = 0; j < EPT; ++j) {
        float p = pv[j];
        unsigned int u = __float_as_uint(p);
        kk[j] = (u & 0x80000000u) ? ~u : (u | 0x80000000u);  // ascending-ordered key
        lb[j] = (lv[j] != 0.0f) ? 1u : 0u;
        float e  = __expf(1.702f * p);                       // v_exp_f32, monotone
        float tt = (float)NB * __builtin_amdgcn_rcpf(1.0f + e); // monotone decr in p
        int b = (int)tt;
        b = b < 0 ? 0 : (b > NB - 1 ? NB - 1 : b);
        bb[j] = b;
        atomicAdd(&cursor[b], 0x10000u + lb[j]);             // (all+=1, pos+=label)
    }
    __syncthreads();

    // ---- packed exclusive scan: cursor -> binstart ----
    unsigned int run[EPT];
    unsigned int s = 0;
    #pragma unroll
    for (int j = 0; j < EPT; ++j) { run[j] = s; s += cursor[t * EPT + j]; }
    unsigned int x = s;
    #pragma unroll
    for (int d = 1; d < 64; d <<= 1) {
        unsigned int y = __shfl_up(x, (unsigned)d, 64);
        if (lane >= d) x += y;
    }
    if (lane == 63) uw[wid] = x;
    __syncthreads();
    if (t == 0) {
        unsigned int a = 0;
        for (int w = 0; w < 4; ++w) { unsigned int v = uw[w]; uw[4 + w] = a; a += v; }
        binstart[NB] = a;   // total: (2048<<16) | k
    }
    __syncthreads();
    unsigned int base = uw[4 + wid] + (x - s);
    #pragma unroll
    for (int j = 0; j < EPT; ++j) binstart[t * EPT + j] = base + run[j];
    __syncthreads();

    // ---- scatter cursor = all-count start ----
    #pragma unroll
    for (int j = 0; j < EPT; ++j) cursor[t * EPT + j] = binstart[t * EPT + j] >> 16;
    __syncthreads();

    unsigned int pos[EPT];
    #pragma unroll
    for (int j = 0; j < EPT; ++j) pos[j] = atomicAdd(&cursor[bb[j]], 1u);
    #pragma unroll
    for (int j = 0; j < EPT; ++j) skv[pos[j]] = make_uint2(kk[j], lb[j]);
    __syncthreads();

    // ---- refine positives only; accumulate precision terms ----
    float part = 0.0f;
    #pragma unroll
    for (int j = 0; j < EPT; ++j) {
        if (lb[j]) {
            unsigned int b   = (unsigned int)bb[j];
            unsigned int pk0 = binstart[b], pk1 = binstart[b + 1];
            unsigned int s0  = pk0 >> 16, s1 = pk1 >> 16;
            unsigned int jbase = pk0 & 0xFFFFu;
            unsigned int myp = pos[j], myk = kk[j];
            unsigned int r = 0, jo = 0;
            for (unsigned int q = s0; q < s1; ++q) {
                uint2 e = skv[q];
                unsigned int gt = ((e.x > myk) || (e.x == myk && q < myp)) ? 1u : 0u;
                r  += gt;
                jo += gt & e.y;
            }
            float jv = (float)(jbase + jo + 1u);
            float rv = (float)(s0 + r + 1u);
            part += jv * __builtin_amdgcn_rcpf(rv);
        }
    }

    // ---- block reduce, write row score ----
    #pragma unroll
    for (int d = 32; d >= 1; d >>= 1) part += __shfl_down(part, (unsigned)d, 64);
    if (lane == 0) fw[wid] = part;
    __syncthreads();
    if (t == 0) {
        float tot = fw[0] + fw[1] + fw[2] + fw[3];
        unsigned int k = binstart[NB] & 0xFFFFu;
        rowsc[row] = (k > 0u) ? (tot / (float)k) : 0.0f;
    }
}

__global__ __launch_bounds__(1024) void mean_reduce(const float* __restrict__ v,
                                                    float* __restrict__ out)
{
    __shared__ float ws[16];
    int t = threadIdx.x;
    float s = 0.f;
    for (int i = t; i < NROWS; i += 1024) s += v[i];
    int lane = t & 63, wid = t >> 6;
    #pragma unroll
    for (int d = 32; d >= 1; d >>= 1) s += __shfl_down(s, (unsigned)d, 64);
    if (lane == 0) ws[wid] = s;
    __syncthreads();
    if (t == 0) {
        float a = 0.f;
        for (int w = 0; w < 16; ++w) a += ws[w];
        out[0] = a / (float)NROWS;
    }
}

extern "C" void kernel_launch(void* const* d_in, const int* in_sizes, int n_in,
                              void* d_out, int out_size, void* d_ws, size_t ws_size,
                              hipStream_t stream)
{
    const float* preds  = (const float*)d_in[0];
    const float* labels = (const float*)d_in[1];
    float* rowsc = (float*)d_ws;   // NROWS floats of scratch

    lrap_rows<<<NROWS, NT, 0, stream>>>(preds, labels, rowsc);
    mean_reduce<<<1, 1024, 0, stream>>>(rowsc, (float*)d_out);
}